// Round 3
// baseline (575.036 us; speedup 1.0000x reference)
//
#include <hip/hip_runtime.h>
#include <math.h>

#define T_LEN  65536
#define TPB    1024
#define VECS   (T_LEN / 4)     // 16384 float4 per row
#define VPT    (VECS / TPB)    // 16 vectors per thread
#define UNROLL 4
#define NWAVES (TPB / 64)      // 16
#define EPS    1e-8f

// One block per row; two passes over the row inside the block so the second
// pass (mean-crossing) hits L3: resident working set = 512 blocks x 256 KiB
// = 128 MiB < 256 MiB Infinity Cache.
__global__ __launch_bounds__(TPB, 8) void stat_feat_fused(const float* __restrict__ x,
                                                          float* __restrict__ out) {
    const int row  = blockIdx.x;
    const int tid  = threadIdx.x;
    const int lane = tid & 63;
    const int wave = tid >> 6;

    const float*  __restrict__ xr = x + (size_t)row * T_LEN;
    const float4* __restrict__ xv = (const float4*)xr;

    // ---------------- pass 1: raw moments + extrema + zero-cross ----------------
    float s1 = 0.f, s2 = 0.f, s3 = 0.f, s4 = 0.f, sa = 0.f, ss = 0.f;
    float mx = -__builtin_inff(), mn = __builtin_inff();
    int zc = 0;

    for (int g = 0; g < VPT; g += UNROLL) {
        float4 v[UNROLL];
        int    vi[UNROLL];
#pragma unroll
        for (int u = 0; u < UNROLL; u++) {          // 4 independent loads in flight
            vi[u] = (g + u) * TPB + tid;
            v[u]  = xv[vi[u]];
        }
#pragma unroll
        for (int u = 0; u < UNROLL; u++) {
            float4 w = v[u];
            float prev = __shfl_up(w.w, 1);
            if (lane == 0) prev = (vi[u] > 0) ? xr[4 * vi[u] - 1] : w.x;

            bool sp = prev < 0.f;
            bool b0 = w.x < 0.f, b1 = w.y < 0.f, b2 = w.z < 0.f, b3 = w.w < 0.f;
            zc += (int)(sp != b0) + (int)(b0 != b1) + (int)(b1 != b2) + (int)(b2 != b3);

            float e[4] = {w.x, w.y, w.z, w.w};
#pragma unroll
            for (int j = 0; j < 4; j++) {
                float t  = e[j];
                float t2 = t * t;
                s1 += t;
                s2 = fmaf(t, t, s2);
                s3 = fmaf(t2, t, s3);
                s4 = fmaf(t2, t2, s4);
                float a = fabsf(t);
                sa += a;
                ss += sqrtf(a);
                mx = fmaxf(mx, t);
                mn = fminf(mn, t);
            }
        }
    }

    // wave reduce (64 lanes)
#pragma unroll
    for (int o = 32; o > 0; o >>= 1) {
        s1 += __shfl_down(s1, o);
        s2 += __shfl_down(s2, o);
        s3 += __shfl_down(s3, o);
        s4 += __shfl_down(s4, o);
        sa += __shfl_down(sa, o);
        ss += __shfl_down(ss, o);
        zc += __shfl_down(zc, o);
        mx = fmaxf(mx, __shfl_down(mx, o));
        mn = fminf(mn, __shfl_down(mn, o));
    }

    __shared__ float l[9][NWAVES];
    __shared__ float s_mean;
    if (lane == 0) {
        l[0][wave] = s1; l[1][wave] = s2; l[2][wave] = s3; l[3][wave] = s4;
        l[4][wave] = sa; l[5][wave] = ss; l[6][wave] = mx; l[7][wave] = mn;
        l[8][wave] = (float)zc;
    }
    __syncthreads();

    float S1 = 0.f, S2 = 0.f, S3 = 0.f, S4 = 0.f, SA = 0.f, SS = 0.f, ZC = 0.f;
    float MX = -__builtin_inff(), MN = __builtin_inff();
    if (tid == 0) {
#pragma unroll
        for (int wv = 0; wv < NWAVES; wv++) {
            S1 += l[0][wv]; S2 += l[1][wv]; S3 += l[2][wv]; S4 += l[3][wv];
            SA += l[4][wv]; SS += l[5][wv];
            MX = fmaxf(MX, l[6][wv]); MN = fminf(MN, l[7][wv]);
            ZC += l[8][wv];
        }
        s_mean = S1 / (float)T_LEN;
    }
    __syncthreads();

    // ---------------- pass 2: mean-crossing (reads hit L3) ----------------
    const float m = s_mean;
    int mc = 0;
    for (int g = 0; g < VPT; g += UNROLL) {
        float4 v[UNROLL];
        int    vi[UNROLL];
#pragma unroll
        for (int u = 0; u < UNROLL; u++) {
            vi[u] = (g + u) * TPB + tid;
            v[u]  = xv[vi[u]];
        }
#pragma unroll
        for (int u = 0; u < UNROLL; u++) {
            float4 w = v[u];
            float prev = __shfl_up(w.w, 1);
            if (lane == 0) prev = (vi[u] > 0) ? xr[4 * vi[u] - 1] : w.x;
            bool sp = prev < m;
            bool b0 = w.x < m, b1 = w.y < m, b2 = w.z < m, b3 = w.w < m;
            mc += (int)(sp != b0) + (int)(b0 != b1) + (int)(b1 != b2) + (int)(b2 != b3);
        }
    }
#pragma unroll
    for (int o = 32; o > 0; o >>= 1) mc += __shfl_down(mc, o);

    __syncthreads();                 // l[] reuse ordering
    if (lane == 0) l[0][wave] = (float)mc;
    __syncthreads();

    // ---------------- finalize (thread 0) ----------------
    if (tid == 0) {
        float MC = 0.f;
#pragma unroll
        for (int wv = 0; wv < NWAVES; wv++) MC += l[0][wv];

        const float Tf = (float)T_LEN;
        float mean = S1 / Tf;
        float sq_mean = S2 / Tf;
        float var = (S2 - S1 * S1 / Tf) / (Tf - 1.f);
        var = fmaxf(var, 0.f);
        float stdv = sqrtf(var);
        float rms = sqrtf(sq_mean);
        float peak = MX, peak_neg = MN;
        float ptp = peak - peak_neg;
        float abs_peak = fabsf(peak);
        float crest = abs_peak / (rms + EPS);
        float mean_abs = SA / Tf;
        float shape = rms / (mean_abs + EPS);
        float impulse = abs_peak / (mean_abs + EPS);
        float sqrt_mean = SS / Tf;
        float clearance = abs_peak / (sqrt_mean * sqrt_mean + EPS);
        float ex3 = S3 / Tf;
        float m3 = ex3 - 3.f * mean * sq_mean + 2.f * mean * mean * mean;
        float m4 = S4 / Tf - 4.f * mean * ex3 + 6.f * mean * mean * sq_mean
                   - 3.f * mean * mean * mean * mean;
        float skew = m3 / (stdv * stdv * stdv + EPS);
        float kurt = m4 / (stdv * stdv * stdv * stdv + EPS) - 3.f;
        float zcr = ZC / (Tf - 1.f);
        float mcr = MC / (Tf - 1.f);
        float margin = abs_peak / (sqrt_mean + EPS);

        float* o = out + (size_t)row * 17;
        o[0] = mean;   o[1] = stdv;     o[2] = var;        o[3] = rms;
        o[4] = peak;   o[5] = peak_neg; o[6] = ptp;        o[7] = crest;
        o[8] = shape;  o[9] = impulse;  o[10] = clearance; o[11] = skew;
        o[12] = kurt;  o[13] = zcr;     o[14] = mcr;       o[15] = margin;
        o[16] = S2;
    }
}

extern "C" void kernel_launch(void* const* d_in, const int* in_sizes, int n_in,
                              void* d_out, int out_size, void* d_ws, size_t ws_size,
                              hipStream_t stream) {
    const float* x = (const float*)d_in[0];
    float* out = (float*)d_out;
    const int rows = in_sizes[0] / T_LEN;   // 1024
    stat_feat_fused<<<dim3(rows), dim3(TPB), 0, stream>>>(x, out);
}

// Round 5
// 389.094 us; speedup vs baseline: 1.4779x; 1.4779x over previous
//
#include <hip/hip_runtime.h>
#include <math.h>

#define T_LEN  65536
#define TPB    256
#define VECS   (T_LEN / 4)       // 16384 float4 per row
#define VPT    (VECS / TPB)      // 64 vectors per thread
#define NSUPER (VPT / 4)         // 16 super-iterations of 4 independent loads
#define NWAVES (TPB / 64)        // 4
#define EPS    1e-8f

struct Acc {
    float s1, s2, s3, s4, sa, ss, mx, mn;
    int zc;
};

__device__ __forceinline__ void p1_body(const float4& v, int vi, int lane,
                                        const float* __restrict__ xr, Acc& a) {
    float prev = __shfl_up(v.w, 1);
    if (lane == 0) prev = (vi > 0) ? xr[4 * vi - 1] : v.x;
    bool sp = prev < 0.f;
    bool b0 = v.x < 0.f, b1 = v.y < 0.f, b2 = v.z < 0.f, b3 = v.w < 0.f;
    a.zc += (int)(sp != b0) + (int)(b0 != b1) + (int)(b1 != b2) + (int)(b2 != b3);

    float e0 = v.x, e1 = v.y, e2 = v.z, e3 = v.w;
    a.s1 += e0 + e1 + e2 + e3;
    a.s2 = fmaf(e0, e0, a.s2); a.s2 = fmaf(e1, e1, a.s2);
    a.s2 = fmaf(e2, e2, a.s2); a.s2 = fmaf(e3, e3, a.s2);
    a.s3 = fmaf(e0 * e0, e0, a.s3); a.s3 = fmaf(e1 * e1, e1, a.s3);
    a.s3 = fmaf(e2 * e2, e2, a.s3); a.s3 = fmaf(e3 * e3, e3, a.s3);
    a.s4 = fmaf(e0 * e0, e0 * e0, a.s4); a.s4 = fmaf(e1 * e1, e1 * e1, a.s4);
    a.s4 = fmaf(e2 * e2, e2 * e2, a.s4); a.s4 = fmaf(e3 * e3, e3 * e3, a.s4);
    float a0 = fabsf(e0), a1 = fabsf(e1), a2 = fabsf(e2), a3 = fabsf(e3);
    a.sa += a0 + a1 + a2 + a3;
    a.ss += sqrtf(a0) + sqrtf(a1) + sqrtf(a2) + sqrtf(a3);
    a.mx = fmaxf(fmaxf(a.mx, e0), fmaxf(e1, fmaxf(e2, e3)));
    a.mn = fminf(fminf(a.mn, e0), fminf(e1, fminf(e2, e3)));
}

__device__ __forceinline__ void p2_body(const float4& v, int vi, int lane, float m,
                                        const float* __restrict__ xr, int& mc) {
    float prev = __shfl_up(v.w, 1);
    if (lane == 0) prev = (vi > 0) ? xr[4 * vi - 1] : v.x;
    bool sp = prev < m;
    bool b0 = v.x < m, b1 = v.y < m, b2 = v.z < m, b3 = v.w < m;
    mc += (int)(sp != b0) + (int)(b0 != b1) + (int)(b1 != b2) + (int)(b2 != b3);
}

// One block per row, two passes (pass 2 = mean-crossing, L3-resident).
// MLP via 4 independent named float4 loads per super-iteration — no arrays,
// no min-waves launch bound (round-3 lesson: arrays + VGPR cap => scratch
// spills, 512 MB of extra HBM traffic).
__global__ __launch_bounds__(TPB) void stat_feat_fused(const float* __restrict__ x,
                                                       float* __restrict__ out) {
    const int row  = blockIdx.x;
    const int tid  = threadIdx.x;
    const int lane = tid & 63;
    const int wave = tid >> 6;

    const float*  __restrict__ xr = x + (size_t)row * T_LEN;
    const float4* __restrict__ xv = (const float4*)xr;

    Acc a;
    a.s1 = a.s2 = a.s3 = a.s4 = a.sa = a.ss = 0.f;
    a.mx = -__builtin_inff();
    a.mn = __builtin_inff();
    a.zc = 0;

    for (int g = 0; g < NSUPER; ++g) {
        const int base = g * 4 * TPB + tid;
        const int ia = base, ib = base + TPB, ic = base + 2 * TPB, id = base + 3 * TPB;
        float4 va = xv[ia];      // 4 independent loads in flight
        float4 vb = xv[ib];
        float4 vc = xv[ic];
        float4 vd = xv[id];
        p1_body(va, ia, lane, xr, a);
        p1_body(vb, ib, lane, xr, a);
        p1_body(vc, ic, lane, xr, a);
        p1_body(vd, id, lane, xr, a);
    }

#pragma unroll
    for (int o = 32; o > 0; o >>= 1) {
        a.s1 += __shfl_down(a.s1, o);
        a.s2 += __shfl_down(a.s2, o);
        a.s3 += __shfl_down(a.s3, o);
        a.s4 += __shfl_down(a.s4, o);
        a.sa += __shfl_down(a.sa, o);
        a.ss += __shfl_down(a.ss, o);
        a.zc += __shfl_down(a.zc, o);
        a.mx = fmaxf(a.mx, __shfl_down(a.mx, o));
        a.mn = fminf(a.mn, __shfl_down(a.mn, o));
    }

    __shared__ float l[9][NWAVES];
    __shared__ float s_mean;
    if (lane == 0) {
        l[0][wave] = a.s1; l[1][wave] = a.s2; l[2][wave] = a.s3; l[3][wave] = a.s4;
        l[4][wave] = a.sa; l[5][wave] = a.ss; l[6][wave] = a.mx; l[7][wave] = a.mn;
        l[8][wave] = (float)a.zc;
    }
    __syncthreads();

    float S1 = 0.f, S2 = 0.f, S3 = 0.f, S4 = 0.f, SA = 0.f, SS = 0.f, ZC = 0.f;
    float MX = -__builtin_inff(), MN = __builtin_inff();
    if (tid == 0) {
#pragma unroll
        for (int wv = 0; wv < NWAVES; wv++) {
            S1 += l[0][wv]; S2 += l[1][wv]; S3 += l[2][wv]; S4 += l[3][wv];
            SA += l[4][wv]; SS += l[5][wv];
            MX = fmaxf(MX, l[6][wv]); MN = fminf(MN, l[7][wv]);
            ZC += l[8][wv];
        }
        s_mean = S1 / (float)T_LEN;
    }
    __syncthreads();

    // ---------------- pass 2: mean-crossing (L3-resident re-read) ----------------
    const float m = s_mean;
    int mc = 0;
    for (int g = 0; g < NSUPER; ++g) {
        const int base = g * 4 * TPB + tid;
        const int ia = base, ib = base + TPB, ic = base + 2 * TPB, id = base + 3 * TPB;
        float4 va = xv[ia];
        float4 vb = xv[ib];
        float4 vc = xv[ic];
        float4 vd = xv[id];
        p2_body(va, ia, lane, m, xr, mc);
        p2_body(vb, ib, lane, m, xr, mc);
        p2_body(vc, ic, lane, m, xr, mc);
        p2_body(vd, id, lane, m, xr, mc);
    }
#pragma unroll
    for (int o = 32; o > 0; o >>= 1) mc += __shfl_down(mc, o);

    __syncthreads();
    if (lane == 0) l[0][wave] = (float)mc;
    __syncthreads();

    if (tid == 0) {
        float MC = 0.f;
#pragma unroll
        for (int wv = 0; wv < NWAVES; wv++) MC += l[0][wv];

        const float Tf = (float)T_LEN;
        float mean = S1 / Tf;
        float sq_mean = S2 / Tf;
        float var = (S2 - S1 * S1 / Tf) / (Tf - 1.f);
        var = fmaxf(var, 0.f);
        float stdv = sqrtf(var);
        float rms = sqrtf(sq_mean);
        float peak = MX, peak_neg = MN;
        float ptp = peak - peak_neg;
        float abs_peak = fabsf(peak);
        float crest = abs_peak / (rms + EPS);
        float mean_abs = SA / Tf;
        float shape = rms / (mean_abs + EPS);
        float impulse = abs_peak / (mean_abs + EPS);
        float sqrt_mean = SS / Tf;
        float clearance = abs_peak / (sqrt_mean * sqrt_mean + EPS);
        float ex3 = S3 / Tf;
        float m3 = ex3 - 3.f * mean * sq_mean + 2.f * mean * mean * mean;
        float m4 = S4 / Tf - 4.f * mean * ex3 + 6.f * mean * mean * sq_mean
                   - 3.f * mean * mean * mean * mean;
        float skew = m3 / (stdv * stdv * stdv + EPS);
        float kurt = m4 / (stdv * stdv * stdv * stdv + EPS) - 3.f;
        float zcr = ZC / (Tf - 1.f);
        float mcr = MC / (Tf - 1.f);
        float margin = abs_peak / (sqrt_mean + EPS);

        float* o = out + (size_t)row * 17;
        o[0] = mean;   o[1] = stdv;     o[2] = var;        o[3] = rms;
        o[4] = peak;   o[5] = peak_neg; o[6] = ptp;        o[7] = crest;
        o[8] = shape;  o[9] = impulse;  o[10] = clearance; o[11] = skew;
        o[12] = kurt;  o[13] = zcr;     o[14] = mcr;       o[15] = margin;
        o[16] = S2;
    }
}

extern "C" void kernel_launch(void* const* d_in, const int* in_sizes, int n_in,
                              void* d_out, int out_size, void* d_ws, size_t ws_size,
                              hipStream_t stream) {
    const float* x = (const float*)d_in[0];
    float* out = (float*)d_out;
    const int rows = in_sizes[0] / T_LEN;   // 1024
    stat_feat_fused<<<dim3(rows), dim3(TPB), 0, stream>>>(x, out);
}